// Round 7
// baseline (873.073 us; speedup 1.0000x reference)
//
#include <hip/hip_runtime.h>

typedef short short8 __attribute__((ext_vector_type(8)));
typedef float floatx4 __attribute__((ext_vector_type(4)));

constexpr int N_PIX  = 16384;           // 4*64*64 pixels
constexpr int FEAT_N = N_PIX * 256;     // floats per feat buffer
constexpr int WB_L   = 2304 * 256;      // bf16 elems per deform layer
constexpr int WOB_L  = 2304 * 32;       // bf16 elems per offset layer (N pad 32)

__device__ __forceinline__ unsigned short bf16_rn(float v) {
  unsigned u = __float_as_uint(v);
  return (unsigned short)((u + 0x7FFFu + ((u >> 16) & 1u)) >> 16);
}
__device__ __forceinline__ void split_bf16(float v, short& h, short& l) {
  unsigned short hu = bf16_rn(v);
  float hf = __uint_as_float(((unsigned)hu) << 16);
  h = (short)hu;
  l = (short)bf16_rn(v - hf);
}

// ---------------- concat [x;y] NCHW -> feat NHWC (fp32) ----------------
__global__ __launch_bounds__(256) void concat_nhwc(const float* __restrict__ x,
                                                   const float* __restrict__ y,
                                                   float* __restrict__ feat) {
  __shared__ float tile[64][65];
  int bid = blockIdx.x;                 // b*256 + h*4 + ct
  int ct = bid & 3, h = (bid >> 2) & 63, b = bid >> 8;
  int c0 = ct * 64;
  const float* src = (c0 < 128) ? x : y;
  int cs = c0 & 127;
  int t = threadIdx.x;
  int w = t & 63, cl = t >> 6;
#pragma unroll
  for (int i = 0; i < 16; ++i) {
    int c = cl + i * 4;
    tile[c][w] = src[((b * 128 + cs + c) * 64 + h) * 64 + w];
  }
  __syncthreads();
  int c2 = t & 63, wl = t >> 6;
#pragma unroll
  for (int i = 0; i < 16; ++i) {
    int w2 = wl + i * 4;
    feat[((b * 64 + h) * 64 + w2) * 256 + c0 + c2] = tile[c2][w2];
  }
}

// ------------- weight prep: deform_w -> MFMA-fragment-linear hi/lo bf16 -------------
// flat short idx (per layer): ((kc*16 + nt)*64 + lane)*8 + j
//   k = kc*32 + (lane>>4)*8 + j ; o = nt*16 + (lane&15)  [verified r4/r5]
__global__ __launch_bounds__(256) void prep_wb(const float* __restrict__ dw,
                                               unsigned short* __restrict__ wbh,
                                               unsigned short* __restrict__ wbl) {
  int g = blockIdx.x * 256 + threadIdx.x;      // < 3*WB_L
  int l = g / WB_L, r = g % WB_L;
  int j = r & 7, lane = (r >> 3) & 63, nt = (r >> 9) & 15, kc = r >> 13;
  int k = kc * 32 + (lane >> 4) * 8 + j;
  int o = nt * 16 + (lane & 15);
  float w = dw[((l * 256 + o) * 256 + (k & 255)) * 9 + (k >> 8)];
  short h, lo; split_bf16(w, h, lo);
  wbh[g] = (unsigned short)h; wbl[g] = (unsigned short)lo;
}

// offset_w -> frag-linear, N padded 18->32 (pad cols = 0); same encode family.
__global__ __launch_bounds__(256) void prep_wob(const float* __restrict__ ow,
                                                unsigned short* __restrict__ woh,
                                                unsigned short* __restrict__ wol) {
  int g = blockIdx.x * 256 + threadIdx.x;      // < 4*WOB_L
  int l = g / WOB_L, r = g % WOB_L;
  int j = r & 7, lane = (r >> 3) & 63, nt = (r >> 9) & 1, kc = r >> 10;
  int k = kc * 32 + (lane >> 4) * 8 + j;
  int o = nt * 16 + (lane & 15);
  float w = 0.f;
  if (o < 18) w = ow[((l * 18 + o) * 256 + (k & 255)) * 9 + (k >> 8)];
  short h, lo; split_bf16(w, h, lo);
  woh[g] = (unsigned short)h; wol[g] = (unsigned short)lo;
}

// ---- in-kernel C/D map calibration (verified r5): A=I, B[k][n]=k*16+n ----
__device__ __forceinline__ void calibrate_cd(int lane, int* rowmap, int* colmap) {
  const floatx4 z4 = {0.f, 0.f, 0.f, 0.f};
  short8 cA, cB;
  int own = lane & 15, q = (lane >> 4) & 3;
#pragma unroll
  for (int j = 0; j < 8; ++j) {
    int k = q * 8 + j;
    cA[j] = (short)((k == own) ? bf16_rn(1.0f) : 0);
    cB[j] = (short)((k < 16) ? bf16_rn((float)(k * 16 + own)) : 0);
  }
  floatx4 cal = __builtin_amdgcn_mfma_f32_16x16x32_bf16(cA, cB, z4, 0, 0, 0);
#pragma unroll
  for (int r = 0; r < 4; ++r) {
    int v = (int)(cal[r] + 0.5f);
    rowmap[r] = (v >> 4) & 15;
    colmap[r] = v & 15;
  }
}

// ---------------- deform conv: wave-autonomous direct-frag gather + MFMA ----------------
// 256 blocks (XCD-swizzled), 4 waves/block; wave owns 16 px × 256 oc.
// Lane L holds A(m=L&15, k=(L>>4)*8+j) gathered DIRECTLY from feat (no LDS/barriers
// in the K-loop). B read frag-linear from global (L2/L1). Calibrated epilogue.
__global__ __launch_bounds__(256) void deform_direct(
    const float* __restrict__ feat, const float* __restrict__ off,
    const unsigned short* __restrict__ wbh, const unsigned short* __restrict__ wbl,
    float* __restrict__ out) {
  __shared__ float cy[9][64], cx[9][64];
  const int t = threadIdx.x;
  const int lane = t & 63;
  const int wv = t >> 6;
  const int bid = blockIdx.x;
  const int tile = (bid & 7) * 32 + (bid >> 3);   // XCD swizzle: 32 tiles/XCD
  const int pblk = tile * 64;                     // block's 64-pixel base
  const int bimg = pblk >> 12, hblk = (pblk >> 6) & 63;
  const float* fbase = feat + bimg * (4096 * 256);

  {  // coords for the block's 64 px
    int mb = t & 63, p = pblk + mb;
    for (int tap = t >> 6; tap < 9; tap += 4) {
      cy[tap][mb] = off[p * 18 + 2 * tap]     + (float)(tap / 3 - 1 + hblk);
      cx[tap][mb] = off[p * 18 + 2 * tap + 1] + (float)(tap % 3 - 1 + mb);
    }
  }
  __syncthreads();   // only barrier in the kernel

  const int m  = lane & 15;           // pixel within wave tile
  const int q  = lane >> 4;           // k-quad (8-ch subgroup)
  const int mb = wv * 16 + m;         // pixel within block (cy/cx index)
  const int pbase = pblk + wv * 16;   // wave's first pixel

  int rowmap[4], colmap[4];
  calibrate_cd(lane, rowmap, colmap);

  floatx4 acc[16];
  const floatx4 z4 = {0.f, 0.f, 0.f, 0.f};
#pragma unroll
  for (int i = 0; i < 16; ++i) acc[i] = z4;

  const short8* BH = (const short8*)wbh;
  const short8* BL = (const short8*)wbl;

  float4 pf[8];
  float w4[4];
  auto issue = [&](int kc) {
    int tap = kc >> 3, c0 = (kc & 7) * 32 + q * 8;
    float py = cy[tap][mb], px = cx[tap][mb];
    float fy = floorf(py), fx = floorf(px);
    int iy = (int)fy, ix = (int)fx;
    float wy1 = py - fy, wx1 = px - fx;
    float wy0 = 1.f - wy1, wx0 = 1.f - wx1;
    w4[0] = wy0 * wx0; w4[1] = wy0 * wx1; w4[2] = wy1 * wx0; w4[3] = wy1 * wx1;
#pragma unroll
    for (int c = 0; c < 4; ++c) {
      int yy = iy + (c >> 1), xx = ix + (c & 1);
      bool ok = ((unsigned)yy < 64u) && ((unsigned)xx < 64u);
      if (!ok) w4[c] = 0.f;
      int yc = min(max(yy, 0), 63), xc = min(max(xx, 0), 63);
      const float4* p = (const float4*)(fbase + (yc * 64 + xc) * 256 + c0);
      pf[c * 2]     = p[0];
      pf[c * 2 + 1] = p[1];
    }
  };

  issue(0);
  for (int kc = 0; kc < 72; ++kc) {
    int bbase = kc * 16 * 64 + lane;
    short8 nbh = BH[bbase], nbl = BL[bbase];   // first B pair, early

    // combine corners -> lane's A frag (hi/lo)
    const float* pfp = (const float*)pf;
    short8 ah, al;
#pragma unroll
    for (int j = 0; j < 8; ++j) {
      float v = w4[0] * pfp[j] + w4[1] * pfp[8 + j] + w4[2] * pfp[16 + j] +
                w4[3] * pfp[24 + j];
      short hh, ll; split_bf16(v, hh, ll);
      ah[j] = hh; al[j] = ll;
    }

    if (kc + 1 < 72) issue(kc + 1);            // prefetch next gather

#pragma unroll
    for (int ni = 0; ni < 16; ++ni) {
      short8 bh = nbh, bl = nbl;
      if (ni < 15) { nbh = BH[bbase + (ni + 1) * 64]; nbl = BL[bbase + (ni + 1) * 64]; }
      acc[ni] = __builtin_amdgcn_mfma_f32_16x16x32_bf16(ah, bh, acc[ni], 0, 0, 0);
      acc[ni] = __builtin_amdgcn_mfma_f32_16x16x32_bf16(ah, bl, acc[ni], 0, 0, 0);
      acc[ni] = __builtin_amdgcn_mfma_f32_16x16x32_bf16(al, bh, acc[ni], 0, 0, 0);
    }
  }

  // calibrated epilogue -> NHWC fp32
#pragma unroll
  for (int ni = 0; ni < 16; ++ni)
#pragma unroll
    for (int r = 0; r < 4; ++r) {
      int pg = pbase + rowmap[r];
      out[pg * 256 + ni * 16 + colmap[r]] = acc[ni][r];
    }
}

// ---------------- offset conv: same skeleton, integer taps, N=32 (18 used) ----------------
template <bool FINAL>
__global__ __launch_bounds__(256) void off_direct(
    const float* __restrict__ feat,
    const unsigned short* __restrict__ woh, const unsigned short* __restrict__ wol,
    float* __restrict__ out) {
  const int t = threadIdx.x;
  const int lane = t & 63;
  const int wv = t >> 6;
  const int bid = blockIdx.x;
  const int tile = (bid & 7) * 32 + (bid >> 3);
  const int pblk = tile * 64;
  const int bimg = pblk >> 12, hblk = (pblk >> 6) & 63;
  const float* fbase = feat + bimg * (4096 * 256);

  const int m = lane & 15, q = lane >> 4;
  const int pbase = pblk + wv * 16;
  const int wpix = (pbase & 63) + m;        // this lane's pixel w coordinate

  int rowmap[4], colmap[4];
  calibrate_cd(lane, rowmap, colmap);

  floatx4 acc[2];
  const floatx4 z4 = {0.f, 0.f, 0.f, 0.f};
  acc[0] = z4; acc[1] = z4;

  const short8* BH = (const short8*)woh;
  const short8* BL = (const short8*)wol;

  float4 pf[2];
  float okf;
  auto issue = [&](int kc) {
    int tap = kc >> 3, c0 = (kc & 7) * 32 + q * 8;
    int yy = hblk + tap / 3 - 1, xx = wpix + tap % 3 - 1;
    bool ok = ((unsigned)yy < 64u) && ((unsigned)xx < 64u);
    okf = ok ? 1.f : 0.f;
    int yc = min(max(yy, 0), 63), xc = min(max(xx, 0), 63);
    const float4* p = (const float4*)(fbase + (yc * 64 + xc) * 256 + c0);
    pf[0] = p[0]; pf[1] = p[1];
  };

  issue(0);
  for (int kc = 0; kc < 72; ++kc) {
    int bbase = kc * 2 * 64 + lane;
    short8 nbh = BH[bbase], nbl = BL[bbase];

    const float* pfp = (const float*)pf;
    short8 ah, al;
#pragma unroll
    for (int j = 0; j < 8; ++j) {
      short hh, ll; split_bf16(okf * pfp[j], hh, ll);
      ah[j] = hh; al[j] = ll;
    }

    if (kc + 1 < 72) issue(kc + 1);

#pragma unroll
    for (int ni = 0; ni < 2; ++ni) {
      short8 bh = nbh, bl = nbl;
      if (ni < 1) { nbh = BH[bbase + 64]; nbl = BL[bbase + 64]; }
      acc[ni] = __builtin_amdgcn_mfma_f32_16x16x32_bf16(ah, bh, acc[ni], 0, 0, 0);
      acc[ni] = __builtin_amdgcn_mfma_f32_16x16x32_bf16(ah, bl, acc[ni], 0, 0, 0);
      acc[ni] = __builtin_amdgcn_mfma_f32_16x16x32_bf16(al, bh, acc[ni], 0, 0, 0);
    }
  }

#pragma unroll
  for (int ni = 0; ni < 2; ++ni)
#pragma unroll
    for (int r = 0; r < 4; ++r) {
      int oc = ni * 16 + colmap[r];
      if (oc < 18) {
        int pg = pbase + rowmap[r];
        if (FINAL)
          out[(bimg * 18 + oc) * 4096 + (pg & 4095)] = acc[ni][r];
        else
          out[pg * 18 + oc] = acc[ni][r];
      }
    }
}

// ---------------- launcher ----------------
// ws budget (evidence: round 5 passed with 42,475,520 B):
//   fA/fB 33,554,432 + wb hi/lo 7,077,888 + wob hi/lo 1,179,648 = 41,811,968 B.
// Intermediate offsets live in d_out (exactly OFF_N floats); the final
// off_direct<true> fully overwrites d_out in NCHW order.
extern "C" void kernel_launch(void* const* d_in, const int* in_sizes, int n_in,
                              void* d_out, int out_size, void* d_ws, size_t ws_size,
                              hipStream_t stream) {
  const float* x  = (const float*)d_in[0];
  const float* y  = (const float*)d_in[1];
  const float* ow = (const float*)d_in[2];   // [4][18][256][3][3]
  const float* dw = (const float*)d_in[3];   // [3][256][256][3][3]
  float* out = (float*)d_out;

  float* fA      = (float*)d_ws;
  float* fB      = fA + FEAT_N;
  unsigned short* wbh  = (unsigned short*)(fB + FEAT_N);
  unsigned short* wbl  = wbh + 3 * WB_L;
  unsigned short* wobh = wbl + 3 * WB_L;
  unsigned short* wobl = wobh + 4 * WOB_L;
  float* off_buf = out;                      // d_out doubles as offset scratch

  concat_nhwc<<<dim3(1024), dim3(256), 0, stream>>>(x, y, fA);
  prep_wb<<<dim3(3 * WB_L / 256), dim3(256), 0, stream>>>(dw, wbh, wbl);
  prep_wob<<<dim3(4 * WOB_L / 256), dim3(256), 0, stream>>>(ow, wobh, wobl);

  float* cur = fA;
  float* nxt = fB;
  for (int i = 0; i < 3; ++i) {
    off_direct<false><<<dim3(256), dim3(256), 0, stream>>>(
        cur, wobh + i * WOB_L, wobl + i * WOB_L, off_buf);
    deform_direct<<<dim3(256), dim3(256), 0, stream>>>(
        cur, off_buf, wbh + i * WB_L, wbl + i * WB_L, nxt);
    float* tmp = cur; cur = nxt; nxt = tmp;
  }
  off_direct<true><<<dim3(256), dim3(256), 0, stream>>>(
      cur, wobh + 3 * WOB_L, wobl + 3 * WOB_L, out);
}